// Round 6
// baseline (1227.158 us; speedup 1.0000x reference)
//
#include <hip/hip_runtime.h>
#include <hip/hip_bf16.h>

#define N_NODESC 100000
#define N_EDGESC 3200000
#define FDIM 512
#define HDIM 256
#define MPAD 100096   // 782 * 128

typedef __attribute__((ext_vector_type(4))) float f32x4;
typedef __attribute__((ext_vector_type(8))) __bf16 bf16x8;
typedef __attribute__((ext_vector_type(4))) __bf16 bf16x4;
typedef unsigned long long u64;

__device__ __forceinline__ void gload_lds16(const void* g, void* l) {
  __builtin_amdgcn_global_load_lds(
      (const __attribute__((address_space(1))) unsigned int*)g,
      (__attribute__((address_space(3))) unsigned int*)l, 16, 0, 0);
}

// ---- x: f32 -> bf16, pad rows [N_NODES, MPAD) with zeros ----
__global__ void k_convert_x(const float* __restrict__ x, __bf16* __restrict__ xb) {
  long i = (long)blockIdx.x * blockDim.x + threadIdx.x;   // one per 8 elements
  long total = (long)MPAD * FDIM / 8;
  if (i >= total) return;
  long base = i * 8;
  long row = base >> 9;
  bf16x8 o;
  if (row < N_NODESC) {
    const float4* p = (const float4*)(x + base);
    float4 a = p[0], b = p[1];
    o[0] = (__bf16)a.x; o[1] = (__bf16)a.y; o[2] = (__bf16)a.z; o[3] = (__bf16)a.w;
    o[4] = (__bf16)b.x; o[5] = (__bf16)b.y; o[6] = (__bf16)b.z; o[7] = (__bf16)b.w;
  } else {
    #pragma unroll
    for (int t = 0; t < 8; ++t) o[t] = (__bf16)0.0f;
  }
  *(bf16x8*)(xb + base) = o;
}

// ---- weight: f32 [K][N] -> bf16 transposed wT [N][K] ----
__global__ void k_convert_wT(const float* __restrict__ w, __bf16* __restrict__ wT) {
  int i = blockIdx.x * 256 + threadIdx.x;
  if (i >= FDIM * FDIM) return;
  int k = i >> 9, n = i & (FDIM - 1);
  wT[n * FDIM + k] = (__bf16)w[i];
}

// ---- CSR build ----
__global__ void k_hist(const int* __restrict__ rows, int* __restrict__ row_off) {
  int e = blockIdx.x * 256 + threadIdx.x;
  if (e >= N_EDGESC) return;
  atomicAdd(&row_off[rows[e] + 1], 1);
}

__global__ __launch_bounds__(1024) void k_scan(int* __restrict__ row_off,
                                               int* __restrict__ row_cur) {
  __shared__ int part[1024];
  const int t = threadIdx.x;
  const int CH = (N_NODESC + 1023) / 1024;  // 98
  const int lo = t * CH;
  const int hi = min(lo + CH, N_NODESC);
  int s = 0;
  for (int i = lo; i < hi; ++i) s += row_off[1 + i];
  part[t] = s;
  __syncthreads();
  for (int d = 1; d < 1024; d <<= 1) {
    int v = part[t];
    int u = (t >= d) ? part[t - d] : 0;
    __syncthreads();
    part[t] = v + u;
    __syncthreads();
  }
  int run = (t == 0) ? 0 : part[t - 1];
  for (int i = lo; i < hi; ++i) {
    row_cur[i] = run;
    run += row_off[1 + i];
    row_off[1 + i] = run;
  }
  if (t == 0) row_off[0] = 0;
}

__global__ void k_scatter(const int* __restrict__ rows, const int* __restrict__ cols,
                          const float* __restrict__ vals, int* __restrict__ row_cur,
                          u64* __restrict__ edges) {
  int e = blockIdx.x * 256 + threadIdx.x;
  if (e >= N_EDGESC) return;
  const int p = atomicAdd(&row_cur[rows[e]], 1);
  edges[p] = ((u64)__float_as_uint(vals[e]) << 32) | (unsigned)cols[e];
}

// ---- GEMM (R3-proven): support halves = xb @ w; epilogue splits N into L/R ----
__global__ __launch_bounds__(256) void k_gemm(const __bf16* __restrict__ xb,
                                              const __bf16* __restrict__ wT,
                                              __bf16* __restrict__ supL,
                                              __bf16* __restrict__ supR) {
  __shared__ __bf16 lA[2][128 * 32];
  __shared__ __bf16 lB[2][128 * 32];   // n-major: lB[n][k]
  const int tm = blockIdx.x >> 2;
  const int tn = blockIdx.x & 3;
  const int tid = threadIdx.x;
  const int wid = tid >> 6;
  const int lane = tid & 63;
  const int wm = wid >> 1;
  const int wn = wid & 1;

  const long rowA0 = (long)tm * 128;
  const int  ncol0 = tn * 128;

  const int srow  = lane >> 2;
  const int skoff = (lane & 3) * 8;

  f32x4 acc[4][4];
  #pragma unroll
  for (int m = 0; m < 4; ++m)
    #pragma unroll
    for (int n = 0; n < 4; ++n)
      acc[m][n] = (f32x4){0.f, 0.f, 0.f, 0.f};

  auto stage = [&](int buf, int kt) {
    const int k0 = kt * 32;
    #pragma unroll
    for (int it = 0; it < 2; ++it) {
      const int c = wid * 2 + it;               // chunk 0..7 (wave-uniform)
      const __bf16* gA = xb + (rowA0 + c * 16 + srow) * (long)FDIM + k0 + skoff;
      gload_lds16(gA, &lA[buf][c * 512]);
      const __bf16* gB = wT + (long)(ncol0 + c * 16 + srow) * FDIM + k0 + skoff;
      gload_lds16(gB, &lB[buf][c * 512]);
    }
  };

  stage(0, 0);
  __syncthreads();

  const int frow = lane & 15;
  const int fk   = (lane >> 4) * 8;

  for (int kt = 0; kt < 16; ++kt) {
    const int buf = kt & 1;
    if (kt + 1 < 16) stage(buf ^ 1, kt + 1);
    bf16x8 a[4], b[4];
    #pragma unroll
    for (int m = 0; m < 4; ++m)
      a[m] = *(const bf16x8*)&lA[buf][(wm * 64 + m * 16 + frow) * 32 + fk];
    #pragma unroll
    for (int n = 0; n < 4; ++n)
      b[n] = *(const bf16x8*)&lB[buf][(wn * 64 + n * 16 + frow) * 32 + fk];
    #pragma unroll
    for (int m = 0; m < 4; ++m)
      #pragma unroll
      for (int n = 0; n < 4; ++n)
        acc[m][n] = __builtin_amdgcn_mfma_f32_16x16x32_bf16(a[m], b[n], acc[m][n], 0, 0, 0);
    __syncthreads();
  }

  // C/D layout (m89-verified): col = lane&15, row = (lane>>4)*4 + i
  // half select: tn<2 -> L, else R (uniform per block)
  __bf16* half = (tn < 2) ? supL : supR;
  const int  hcol0 = (ncol0 & 255) + wn * 64 + frow;
  const long crow0 = (long)tm * 128 + wm * 64 + (lane >> 4) * 4;
  #pragma unroll
  for (int m = 0; m < 4; ++m)
    #pragma unroll
    for (int n = 0; n < 4; ++n)
      #pragma unroll
      for (int i = 0; i < 4; ++i)
        half[(crow0 + m * 16 + i) * (long)HDIM + hcol0 + n * 16] = (__bf16)acc[m][n][i];
}

// ---- SpMM half-pass: one wave per row, lane owns 4 feats of this half ----
__global__ __launch_bounds__(256) void k_spmm(const int* __restrict__ row_off,
                                              const u64* __restrict__ edges,
                                              const __bf16* __restrict__ sup,
                                              float* __restrict__ outp) {
  const int r = blockIdx.x * 4 + (threadIdx.x >> 6);
  const int lane = threadIdx.x & 63;
  if (r >= N_NODESC) return;
  const int beg = row_off[r];
  const int end = row_off[r + 1];
  const __bf16* sp = sup + lane * 4;

  float a0 = 0.f, a1 = 0.f, a2 = 0.f, a3 = 0.f;

  int j = beg;
  for (; j + 1 < end; j += 2) {
    const u64 e0 = edges[j];
    const u64 e1 = edges[j + 1];
    const bf16x4 s0 = *(const bf16x4*)(sp + (long)(unsigned)(e0 & 0xffffffffu) * HDIM);
    const bf16x4 s1 = *(const bf16x4*)(sp + (long)(unsigned)(e1 & 0xffffffffu) * HDIM);
    const float v0 = __uint_as_float((unsigned)(e0 >> 32));
    const float v1 = __uint_as_float((unsigned)(e1 >> 32));
    a0 += v0 * (float)s0[0]; a1 += v0 * (float)s0[1];
    a2 += v0 * (float)s0[2]; a3 += v0 * (float)s0[3];
    a0 += v1 * (float)s1[0]; a1 += v1 * (float)s1[1];
    a2 += v1 * (float)s1[2]; a3 += v1 * (float)s1[3];
  }
  if (j < end) {
    const u64 e0 = edges[j];
    const bf16x4 s0 = *(const bf16x4*)(sp + (long)(unsigned)(e0 & 0xffffffffu) * HDIM);
    const float v0 = __uint_as_float((unsigned)(e0 >> 32));
    a0 += v0 * (float)s0[0]; a1 += v0 * (float)s0[1];
    a2 += v0 * (float)s0[2]; a3 += v0 * (float)s0[3];
  }

  *(f32x4*)(outp + (long)r * FDIM + lane * 4) = (f32x4){a0, a1, a2, a3};
}

extern "C" void kernel_launch(void* const* d_in, const int* in_sizes, int n_in,
                              void* d_out, int out_size, void* d_ws, size_t ws_size,
                              hipStream_t stream) {
  const float* x    = (const float*)d_in[0];
  const float* w    = (const float*)d_in[1];
  const int*   rows = (const int*)d_in[2];
  const int*   cols = (const int*)d_in[3];
  const float* vals = (const float*)d_in[4];
  float* out = (float*)d_out;

  char* ws = (char*)d_ws;
  size_t off = 0;
  auto alloc = [&](size_t bytes) {
    void* p = ws + off;
    off += (bytes + 255) & ~(size_t)255;
    return p;
  };
  __bf16* xb      = (__bf16*)alloc((size_t)MPAD * FDIM * 2);      // 102.5 MB
  __bf16* wT      = (__bf16*)alloc((size_t)FDIM * FDIM * 2);      // 0.5 MB
  __bf16* supL    = (__bf16*)alloc((size_t)MPAD * HDIM * 2);      // 51.2 MB
  __bf16* supR    = (__bf16*)alloc((size_t)MPAD * HDIM * 2);      // 51.2 MB
  int*    row_off = (int*)alloc((size_t)(N_NODESC + 1) * 4);
  int*    row_cur = (int*)alloc((size_t)(N_NODESC + 1) * 4);
  u64*    edges   = (u64*)alloc((size_t)N_EDGESC * 8);            // 25.6 MB
  (void)ws_size;

  hipMemsetAsync(row_off, 0, (size_t)(N_NODESC + 1) * 4, stream);

  k_convert_x<<<(int)(((long)MPAD * FDIM / 8 + 255) / 256), 256, 0, stream>>>(x, xb);
  k_convert_wT<<<(FDIM * FDIM + 255) / 256, 256, 0, stream>>>(w, wT);
  k_hist<<<(N_EDGESC + 255) / 256, 256, 0, stream>>>(rows, row_off);
  k_scan<<<1, 1024, 0, stream>>>(row_off, row_cur);
  k_scatter<<<(N_EDGESC + 255) / 256, 256, 0, stream>>>(rows, cols, vals, row_cur, edges);
  k_gemm<<<(MPAD / 128) * 4, 256, 0, stream>>>(xb, wT, supL, supR);
  k_spmm<<<N_NODESC / 4, 256, 0, stream>>>(row_off, edges, supL, out);
  k_spmm<<<N_NODESC / 4, 256, 0, stream>>>(row_off, edges, supR, out + HDIM);
}

// Round 7
// 874.873 us; speedup vs baseline: 1.4027x; 1.4027x over previous
//
#include <hip/hip_runtime.h>
#include <hip/hip_bf16.h>

#define N_NODESC 100000
#define N_EDGESC 3200000
#define FDIM 512
#define MPAD 100096   // 782 * 128
#define NBLK 256      // chunks for bucket sort
#define EPB 12500     // edges per chunk (256*12500 = 3.2M exactly)
#define NBUCKB 391    // row buckets of 256 rows (391*256 = 100096 >= 100000)
#define NCNT (NBLK * NBUCKB)   // 100096

typedef __attribute__((ext_vector_type(4))) float f32x4;
typedef __attribute__((ext_vector_type(8))) __bf16 bf16x8;
typedef unsigned long long u64;

__device__ __forceinline__ void gload_lds16(const void* g, void* l) {
  __builtin_amdgcn_global_load_lds(
      (const __attribute__((address_space(1))) unsigned int*)g,
      (__attribute__((address_space(3))) unsigned int*)l, 16, 0, 0);
}

// ---- x: f32 -> bf16, pad rows [N_NODES, MPAD) with zeros ----
__global__ void k_convert_x(const float* __restrict__ x, __bf16* __restrict__ xb) {
  long i = (long)blockIdx.x * blockDim.x + threadIdx.x;
  long total = (long)MPAD * FDIM / 8;
  if (i >= total) return;
  long base = i * 8;
  long row = base >> 9;
  bf16x8 o;
  if (row < N_NODESC) {
    const float4* p = (const float4*)(x + base);
    float4 a = p[0], b = p[1];
    o[0] = (__bf16)a.x; o[1] = (__bf16)a.y; o[2] = (__bf16)a.z; o[3] = (__bf16)a.w;
    o[4] = (__bf16)b.x; o[5] = (__bf16)b.y; o[6] = (__bf16)b.z; o[7] = (__bf16)b.w;
  } else {
    #pragma unroll
    for (int t = 0; t < 8; ++t) o[t] = (__bf16)0.0f;
  }
  *(bf16x8*)(xb + base) = o;
}

// ---- weight: f32 [K][N] -> bf16 transposed wT [N][K] ----
__global__ void k_convert_wT(const float* __restrict__ w, __bf16* __restrict__ wT) {
  int i = blockIdx.x * 256 + threadIdx.x;
  if (i >= FDIM * FDIM) return;
  int k = i >> 9, n = i & (FDIM - 1);
  wT[n * FDIM + k] = (__bf16)w[i];
}

// ---- bucket sort pass 1: per-(bucket,chunk) counts via LDS histogram ----
__global__ __launch_bounds__(256) void k_bcount(const int* __restrict__ rows,
                                                int* __restrict__ cnt) {
  __shared__ int h[NBUCKB];
  const int blk = blockIdx.x;
  for (int i = threadIdx.x; i < NBUCKB; i += 256) h[i] = 0;
  __syncthreads();
  const int e0 = blk * EPB;
  for (int e = e0 + threadIdx.x; e < e0 + EPB; e += 256)
    atomicAdd(&h[rows[e] >> 8], 1);
  __syncthreads();
  for (int i = threadIdx.x; i < NBUCKB; i += 256) cnt[i * NBLK + blk] = h[i];
}

// ---- exclusive scan (in-place) over cnt[0..NCNT), total -> cnt[NCNT] ----
__global__ __launch_bounds__(1024) void k_scan(int* __restrict__ cnt) {
  __shared__ int part[1024];
  const int t = threadIdx.x;
  const int CH = (NCNT + 1023) / 1024;   // 98
  const int lo = t * CH;
  const int hi = min(lo + CH, NCNT);
  int s = 0;
  for (int i = lo; i < hi; ++i) s += cnt[i];
  part[t] = s;
  __syncthreads();
  for (int d = 1; d < 1024; d <<= 1) {
    int a = part[t];
    int u = (t >= d) ? part[t - d] : 0;
    __syncthreads();
    part[t] = a + u;
    __syncthreads();
  }
  int run = (t == 0) ? 0 : part[t - 1];
  for (int i = lo; i < hi; ++i) {
    const int c = cnt[i];
    cnt[i] = run;
    run += c;
  }
  if (t == 1023) cnt[NCNT] = part[1023];
}

// ---- bucket sort pass 2: coalesced scatter into (bucket,chunk) runs ----
// pack: val(32) | lrow(8) @bit17 | col(17)
__global__ __launch_bounds__(256) void k_bscatter(const int* __restrict__ rows,
                                                  const int* __restrict__ cols,
                                                  const float* __restrict__ vals,
                                                  const int* __restrict__ off,
                                                  u64* __restrict__ bedges) {
  __shared__ int lofs[NBUCKB];
  __shared__ int lcur[NBUCKB];
  const int blk = blockIdx.x;
  for (int i = threadIdx.x; i < NBUCKB; i += 256) {
    lofs[i] = off[i * NBLK + blk];
    lcur[i] = 0;
  }
  __syncthreads();
  const int e0 = blk * EPB;
  for (int e = e0 + threadIdx.x; e < e0 + EPB; e += 256) {
    const int r = rows[e];
    const int b = r >> 8;
    const int p = lofs[b] + atomicAdd(&lcur[b], 1);
    bedges[p] = ((u64)__float_as_uint(vals[e]) << 32) |
                ((u64)(r & 255) << 17) | (unsigned)cols[e];
  }
}

// ---- CSR finalize: one block per bucket; LDS hist+scan; private-region scatter ----
__global__ __launch_bounds__(256) void k_csr(const int* __restrict__ off,
                                             const u64* __restrict__ bedges,
                                             u64* __restrict__ edges,
                                             int* __restrict__ row_off) {
  __shared__ int hcnt[256];
  __shared__ int hcur[256];
  const int b = blockIdx.x;
  const int t = threadIdx.x;
  const int base  = off[b * NBLK];
  const int nextb = (b + 1 < NBUCKB) ? off[(b + 1) * NBLK] : off[NCNT];
  hcnt[t] = 0;
  __syncthreads();
  for (int j = base + t; j < nextb; j += 256)
    atomicAdd(&hcnt[(int)(bedges[j] >> 17) & 255], 1);
  __syncthreads();
  for (int d = 1; d < 256; d <<= 1) {
    int a = hcnt[t];
    int u = (t >= d) ? hcnt[t - d] : 0;
    __syncthreads();
    hcnt[t] = a + u;
    __syncthreads();
  }
  const int excl = (t == 0) ? 0 : hcnt[t - 1];
  row_off[b * 256 + t] = base + excl;
  hcur[t] = base + excl;
  __syncthreads();
  for (int j = base + t; j < nextb; j += 256) {
    const u64 e = bedges[j];
    const int lr = (int)(e >> 17) & 255;
    const int p = atomicAdd(&hcur[lr], 1);
    edges[p] = (e & 0xFFFFFFFF00000000ull) | (e & 0x1FFFFull);
  }
}

// ---- GEMM (R3-proven): support[MPAD][512] = xb @ w ----
__global__ __launch_bounds__(256) void k_gemm(const __bf16* __restrict__ xb,
                                              const __bf16* __restrict__ wT,
                                              __bf16* __restrict__ support) {
  __shared__ __bf16 lA[2][128 * 32];
  __shared__ __bf16 lB[2][128 * 32];   // n-major: lB[n][k]
  const int tm = blockIdx.x >> 2;
  const int tn = blockIdx.x & 3;
  const int tid = threadIdx.x;
  const int wid = tid >> 6;
  const int lane = tid & 63;
  const int wm = wid >> 1;
  const int wn = wid & 1;

  const long rowA0 = (long)tm * 128;
  const int  ncol0 = tn * 128;

  const int srow  = lane >> 2;
  const int skoff = (lane & 3) * 8;

  f32x4 acc[4][4];
  #pragma unroll
  for (int m = 0; m < 4; ++m)
    #pragma unroll
    for (int n = 0; n < 4; ++n)
      acc[m][n] = (f32x4){0.f, 0.f, 0.f, 0.f};

  auto stage = [&](int buf, int kt) {
    const int k0 = kt * 32;
    #pragma unroll
    for (int it = 0; it < 2; ++it) {
      const int c = wid * 2 + it;
      const __bf16* gA = xb + (rowA0 + c * 16 + srow) * (long)FDIM + k0 + skoff;
      gload_lds16(gA, &lA[buf][c * 512]);
      const __bf16* gB = wT + (long)(ncol0 + c * 16 + srow) * FDIM + k0 + skoff;
      gload_lds16(gB, &lB[buf][c * 512]);
    }
  };

  stage(0, 0);
  __syncthreads();

  const int frow = lane & 15;
  const int fk   = (lane >> 4) * 8;

  for (int kt = 0; kt < 16; ++kt) {
    const int buf = kt & 1;
    if (kt + 1 < 16) stage(buf ^ 1, kt + 1);
    bf16x8 a[4], b[4];
    #pragma unroll
    for (int m = 0; m < 4; ++m)
      a[m] = *(const bf16x8*)&lA[buf][(wm * 64 + m * 16 + frow) * 32 + fk];
    #pragma unroll
    for (int n = 0; n < 4; ++n)
      b[n] = *(const bf16x8*)&lB[buf][(wn * 64 + n * 16 + frow) * 32 + fk];
    #pragma unroll
    for (int m = 0; m < 4; ++m)
      #pragma unroll
      for (int n = 0; n < 4; ++n)
        acc[m][n] = __builtin_amdgcn_mfma_f32_16x16x32_bf16(a[m], b[n], acc[m][n], 0, 0, 0);
    __syncthreads();
  }

  // C/D layout (m89-verified): col = lane&15, row = (lane>>4)*4 + i
  const long crow0 = (long)tm * 128 + wm * 64 + (lane >> 4) * 4;
  const int  ccol0 = tn * 128 + wn * 64 + frow;
  #pragma unroll
  for (int m = 0; m < 4; ++m)
    #pragma unroll
    for (int n = 0; n < 4; ++n)
      #pragma unroll
      for (int i = 0; i < 4; ++i)
        support[(crow0 + m * 16 + i) * (long)FDIM + ccol0 + n * 16] = (__bf16)acc[m][n][i];
}

// ---- SpMM (R3-proven): one wave per row, lane owns 8 features, f32 acc ----
__global__ __launch_bounds__(256) void k_spmm(const int* __restrict__ row_off,
                                              const u64* __restrict__ edges,
                                              const __bf16* __restrict__ support,
                                              float* __restrict__ out) {
  const int r = blockIdx.x * 4 + (threadIdx.x >> 6);
  const int lane = threadIdx.x & 63;
  if (r >= N_NODESC) return;
  const int beg = row_off[r];
  const int end = row_off[r + 1];
  const __bf16* sp = support + lane * 8;

  float acc[8];
  #pragma unroll
  for (int i = 0; i < 8; ++i) acc[i] = 0.f;

  int j = beg;
  for (; j + 1 < end; j += 2) {
    const u64 e0 = edges[j];
    const u64 e1 = edges[j + 1];
    const bf16x8 s0 = *(const bf16x8*)(sp + (long)(unsigned)(e0 & 0xffffffffu) * FDIM);
    const bf16x8 s1 = *(const bf16x8*)(sp + (long)(unsigned)(e1 & 0xffffffffu) * FDIM);
    const float v0 = __uint_as_float((unsigned)(e0 >> 32));
    const float v1 = __uint_as_float((unsigned)(e1 >> 32));
    #pragma unroll
    for (int i = 0; i < 8; ++i) acc[i] += v0 * (float)s0[i];
    #pragma unroll
    for (int i = 0; i < 8; ++i) acc[i] += v1 * (float)s1[i];
  }
  if (j < end) {
    const u64 e0 = edges[j];
    const bf16x8 s0 = *(const bf16x8*)(sp + (long)(unsigned)(e0 & 0xffffffffu) * FDIM);
    const float v0 = __uint_as_float((unsigned)(e0 >> 32));
    #pragma unroll
    for (int i = 0; i < 8; ++i) acc[i] += v0 * (float)s0[i];
  }

  *(float4*)(out + (long)r * FDIM + lane * 8) =
      make_float4(acc[0], acc[1], acc[2], acc[3]);
  *(float4*)(out + (long)r * FDIM + lane * 8 + 4) =
      make_float4(acc[4], acc[5], acc[6], acc[7]);
}

extern "C" void kernel_launch(void* const* d_in, const int* in_sizes, int n_in,
                              void* d_out, int out_size, void* d_ws, size_t ws_size,
                              hipStream_t stream) {
  const float* x    = (const float*)d_in[0];
  const float* w    = (const float*)d_in[1];
  const int*   rows = (const int*)d_in[2];
  const int*   cols = (const int*)d_in[3];
  const float* vals = (const float*)d_in[4];
  float* out = (float*)d_out;

  char* ws = (char*)d_ws;
  size_t off = 0;
  auto alloc = [&](size_t bytes) {
    void* p = ws + off;
    off += (bytes + 255) & ~(size_t)255;
    return p;
  };
  __bf16* xb      = (__bf16*)alloc((size_t)MPAD * FDIM * 2);      // 102.5 MB
  __bf16* wT      = (__bf16*)alloc((size_t)FDIM * FDIM * 2);      // 0.5 MB
  __bf16* support = (__bf16*)alloc((size_t)MPAD * FDIM * 2);      // 102.5 MB
  int*    cnt     = (int*)alloc((size_t)(NCNT + 1) * 4);          // 0.4 MB
  int*    row_off = (int*)alloc((size_t)(MPAD + 1) * 4);          // 0.4 MB
  u64*    edges   = (u64*)alloc((size_t)N_EDGESC * 8);            // 25.6 MB
  u64*    bedges  = (u64*)xb;   // alias: xb is dead after k_gemm
  (void)ws_size;

  k_convert_x<<<(int)(((long)MPAD * FDIM / 8 + 255) / 256), 256, 0, stream>>>(x, xb);
  k_convert_wT<<<(FDIM * FDIM + 255) / 256, 256, 0, stream>>>(w, wT);
  k_bcount<<<NBLK, 256, 0, stream>>>(rows, cnt);
  k_scan<<<1, 1024, 0, stream>>>(cnt);
  k_gemm<<<(MPAD / 128) * 4, 256, 0, stream>>>(xb, wT, support);     // last use of xb
  k_bscatter<<<NBLK, 256, 0, stream>>>(rows, cols, vals, cnt, bedges);
  k_csr<<<NBUCKB, 256, 0, stream>>>(cnt, bedges, edges, row_off);
  k_spmm<<<N_NODESC / 4, 256, 0, stream>>>(row_off, edges, support, out);
}

// Round 8
// 745.842 us; speedup vs baseline: 1.6453x; 1.1730x over previous
//
#include <hip/hip_runtime.h>
#include <hip/hip_bf16.h>

#define N_NODESC 100000
#define N_EDGESC 3200000
#define FDIM 512
#define MPAD 100096   // 391 * 256
#define NBLK 256      // chunks for bucket sort
#define EPB 12500     // edges per chunk (256*12500 = 3.2M exactly)
#define NBUCKB 391    // row buckets of 256 rows
#define NCNT (NBLK * NBUCKB)   // 100096
#define NB_SCAN ((NCNT + 8191) / 8192)   // 13

typedef __attribute__((ext_vector_type(4))) float f32x4;
typedef __attribute__((ext_vector_type(8))) __bf16 bf16x8;
typedef __attribute__((ext_vector_type(4))) __bf16 bf16x4;
typedef unsigned long long u64;

__device__ __forceinline__ void gload_lds16(const void* g, void* l) {
  __builtin_amdgcn_global_load_lds(
      (const __attribute__((address_space(1))) unsigned int*)g,
      (__attribute__((address_space(3))) unsigned int*)l, 16, 0, 0);
}

// ---- weight: f32 [K][N] -> bf16 transposed wT [N][K] ----
__global__ void k_convert_wT(const float* __restrict__ w, __bf16* __restrict__ wT) {
  int i = blockIdx.x * 256 + threadIdx.x;
  if (i >= FDIM * FDIM) return;
  int k = i >> 9, n = i & (FDIM - 1);
  wT[n * FDIM + k] = (__bf16)w[i];
}

// ---- bucket sort pass 1: per-(bucket,chunk) counts via LDS histogram ----
__global__ __launch_bounds__(256) void k_bcount(const int* __restrict__ rows,
                                                int* __restrict__ cnt) {
  __shared__ int h[NBUCKB];
  const int blk = blockIdx.x;
  for (int i = threadIdx.x; i < NBUCKB; i += 256) h[i] = 0;
  __syncthreads();
  const int e0 = blk * EPB;
  for (int e = e0 + threadIdx.x; e < e0 + EPB; e += 256)
    atomicAdd(&h[rows[e] >> 8], 1);
  __syncthreads();
  for (int i = threadIdx.x; i < NBUCKB; i += 256) cnt[i * NBLK + blk] = h[i];
}

// ---- multi-block exclusive scan over cnt[0..NCNT) ----
__global__ __launch_bounds__(1024) void k_scan1(int* __restrict__ d, int* __restrict__ bsum) {
  __shared__ int s[1024];
  const int t = threadIdx.x;
  const int base = blockIdx.x * 8192 + t * 8;
  int v[8];
  int sum = 0;
  #pragma unroll
  for (int k = 0; k < 8; ++k) {
    v[k] = (base + k < NCNT) ? d[base + k] : 0;
    sum += v[k];
  }
  s[t] = sum;
  __syncthreads();
  for (int dl = 1; dl < 1024; dl <<= 1) {
    int a = s[t];
    int b = (t >= dl) ? s[t - dl] : 0;
    __syncthreads();
    s[t] = a + b;
    __syncthreads();
  }
  int excl = (t == 0) ? 0 : s[t - 1];
  #pragma unroll
  for (int k = 0; k < 8; ++k) {
    if (base + k < NCNT) d[base + k] = excl;
    excl += v[k];
  }
  if (t == 1023) bsum[blockIdx.x] = s[1023];
}

__global__ __launch_bounds__(1024) void k_scan2(int* __restrict__ bsum, int nb,
                                                int* __restrict__ d) {
  __shared__ int s[1024];
  const int t = threadIdx.x;
  s[t] = (t < nb) ? bsum[t] : 0;
  __syncthreads();
  for (int dl = 1; dl < 1024; dl <<= 1) {
    int a = s[t];
    int b = (t >= dl) ? s[t - dl] : 0;
    __syncthreads();
    s[t] = a + b;
    __syncthreads();
  }
  if (t < nb) bsum[t] = (t == 0) ? 0 : s[t - 1];
  if (t == 0) d[NCNT] = s[1023];
}

__global__ void k_scan3(int* __restrict__ d, const int* __restrict__ bsum) {
  int i = blockIdx.x * 256 + threadIdx.x;
  if (i >= NCNT) return;
  d[i] += bsum[i >> 13];
}

// ---- bucket sort pass 2: scatter into (bucket,chunk) runs ----
// pack: val(32) | lrow(8) @bit17 | col(17)
__global__ __launch_bounds__(256) void k_bscatter(const int* __restrict__ rows,
                                                  const int* __restrict__ cols,
                                                  const float* __restrict__ vals,
                                                  const int* __restrict__ off,
                                                  u64* __restrict__ bedges) {
  __shared__ int lofs[NBUCKB];
  __shared__ int lcur[NBUCKB];
  const int blk = blockIdx.x;
  for (int i = threadIdx.x; i < NBUCKB; i += 256) {
    lofs[i] = off[i * NBLK + blk];
    lcur[i] = 0;
  }
  __syncthreads();
  const int e0 = blk * EPB;
  for (int e = e0 + threadIdx.x; e < e0 + EPB; e += 256) {
    const int r = rows[e];
    const int b = r >> 8;
    const int p = lofs[b] + atomicAdd(&lcur[b], 1);
    bedges[p] = ((u64)__float_as_uint(vals[e]) << 32) |
                ((u64)(r & 255) << 17) | (unsigned)cols[e];
  }
}

// ---- CSR finalize: one block per bucket; LDS hist+scan; private-region scatter ----
__global__ __launch_bounds__(256) void k_csr(const int* __restrict__ off,
                                             const u64* __restrict__ bedges,
                                             u64* __restrict__ edges,
                                             int* __restrict__ row_off) {
  __shared__ int hcnt[256];
  __shared__ int hcur[256];
  const int b = blockIdx.x;
  const int t = threadIdx.x;
  const int base  = off[b * NBLK];
  const int nextb = (b + 1 < NBUCKB) ? off[(b + 1) * NBLK] : off[NCNT];
  hcnt[t] = 0;
  __syncthreads();
  for (int j = base + t; j < nextb; j += 256)
    atomicAdd(&hcnt[(int)(bedges[j] >> 17) & 255], 1);
  __syncthreads();
  for (int d = 1; d < 256; d <<= 1) {
    int a = hcnt[t];
    int u = (t >= d) ? hcnt[t - d] : 0;
    __syncthreads();
    hcnt[t] = a + u;
    __syncthreads();
  }
  const int excl = (t == 0) ? 0 : hcnt[t - 1];
  row_off[b * 256 + t] = base + excl;
  hcur[t] = base + excl;
  __syncthreads();
  for (int j = base + t; j < nextb; j += 256) {
    const u64 e = bedges[j];
    const int lr = (int)(e >> 17) & 255;
    const int p = atomicAdd(&hcur[lr], 1);
    edges[p] = (e & 0xFFFFFFFF00000000ull) | (e & 0x1FFFFull);
  }
}

// ---- GEMM: support[MPAD][512] (bf16) = x (f32, fused convert) @ w ----
// 256x256 tile, BK=32, 8 waves (2m x 4n), A reg-staged f32->bf16, B gload_lds
__global__ __launch_bounds__(512) void k_gemm(const float* __restrict__ x,
                                              const __bf16* __restrict__ wT,
                                              __bf16* __restrict__ support) {
  __shared__ __bf16 lA[2][256 * 32];   // 16KB each
  __shared__ __bf16 lB[2][256 * 32];   // n-major: lB[n][k]
  const int tm = blockIdx.x >> 1;
  const int tn = blockIdx.x & 1;
  const int tid = threadIdx.x;
  const int wid = tid >> 6;
  const int lane = tid & 63;
  const int wm = wid >> 2;      // 0..1
  const int wn = wid & 3;       // 0..3

  const long rowA0 = (long)tm * 256;
  const int  ncol0 = tn * 256;

  // B staging geometry (1KB chunks of 16 n-rows x 32 k)
  const int srow  = lane >> 2;
  const int skoff = (lane & 3) * 8;

  // A staging geometry: thread covers row tid>>1, k-half tid&1 (16 f32)
  const int arow = tid >> 1;        // 0..255
  const int ah   = (tid & 1) * 16;  // 0 or 16

  f32x4 acc[8][4];
  #pragma unroll
  for (int m = 0; m < 8; ++m)
    #pragma unroll
    for (int n = 0; n < 4; ++n)
      acc[m][n] = (f32x4){0.f, 0.f, 0.f, 0.f};

  const long grow = rowA0 + arow;
  const long arowc = (grow < N_NODESC) ? grow : (N_NODESC - 1);
  const bool apad = grow >= N_NODESC;

  float4 ar[4];
  auto issueA = [&](int kt) {
    const int k0 = kt * 32;
    #pragma unroll
    for (int i = 0; i < 4; ++i)
      ar[i] = *(const float4*)(x + arowc * FDIM + k0 + ah + 4 * i);
  };
  auto writeA = [&](int buf) {
    #pragma unroll
    for (int i = 0; i < 4; ++i) {
      bf16x4 o;
      o[0] = (__bf16)(apad ? 0.f : ar[i].x);
      o[1] = (__bf16)(apad ? 0.f : ar[i].y);
      o[2] = (__bf16)(apad ? 0.f : ar[i].z);
      o[3] = (__bf16)(apad ? 0.f : ar[i].w);
      *(bf16x4*)&lA[buf][arow * 32 + ah + 4 * i] = o;
    }
  };
  auto stageB = [&](int buf, int kt) {
    const int k0 = kt * 32;
    #pragma unroll
    for (int it = 0; it < 2; ++it) {
      const int c = wid * 2 + it;   // chunk 0..15 (wave-uniform)
      const __bf16* gB = wT + (long)(ncol0 + c * 16 + srow) * FDIM + k0 + skoff;
      gload_lds16(gB, &lB[buf][c * 512]);
    }
  };

  issueA(0);
  stageB(0, 0);
  writeA(0);
  __syncthreads();

  const int frow = lane & 15;
  const int fk   = (lane >> 4) * 8;

  for (int kt = 0; kt < 16; ++kt) {
    const int buf = kt & 1;
    if (kt < 15) {
      issueA(kt + 1);
      stageB(buf ^ 1, kt + 1);
    }
    bf16x8 a[8], b[4];
    #pragma unroll
    for (int m = 0; m < 8; ++m)
      a[m] = *(const bf16x8*)&lA[buf][(wm * 128 + m * 16 + frow) * 32 + fk];
    #pragma unroll
    for (int n = 0; n < 4; ++n)
      b[n] = *(const bf16x8*)&lB[buf][(wn * 64 + n * 16 + frow) * 32 + fk];
    #pragma unroll
    for (int m = 0; m < 8; ++m)
      #pragma unroll
      for (int n = 0; n < 4; ++n)
        acc[m][n] = __builtin_amdgcn_mfma_f32_16x16x32_bf16(a[m], b[n], acc[m][n], 0, 0, 0);
    if (kt < 15) writeA(buf ^ 1);
    __syncthreads();
  }

  // C/D layout (m89-verified): col = lane&15, row = (lane>>4)*4 + i
  const long crow0 = (long)tm * 256 + wm * 128 + (lane >> 4) * 4;
  const int  ccol0 = tn * 256 + wn * 64 + frow;
  #pragma unroll
  for (int m = 0; m < 8; ++m)
    #pragma unroll
    for (int n = 0; n < 4; ++n)
      #pragma unroll
      for (int i = 0; i < 4; ++i)
        support[(crow0 + m * 16 + i) * (long)FDIM + ccol0 + n * 16] = (__bf16)acc[m][n][i];
}

// ---- SpMM (R3-proven): one wave per row, lane owns 8 features, f32 acc ----
__global__ __launch_bounds__(256) void k_spmm(const int* __restrict__ row_off,
                                              const u64* __restrict__ edges,
                                              const __bf16* __restrict__ support,
                                              float* __restrict__ out) {
  const int r = blockIdx.x * 4 + (threadIdx.x >> 6);
  const int lane = threadIdx.x & 63;
  if (r >= N_NODESC) return;
  const int beg = row_off[r];
  const int end = row_off[r + 1];
  const __bf16* sp = support + lane * 8;

  float acc[8];
  #pragma unroll
  for (int i = 0; i < 8; ++i) acc[i] = 0.f;

  int j = beg;
  for (; j + 1 < end; j += 2) {
    const u64 e0 = edges[j];
    const u64 e1 = edges[j + 1];
    const bf16x8 s0 = *(const bf16x8*)(sp + (long)(unsigned)(e0 & 0xffffffffu) * FDIM);
    const bf16x8 s1 = *(const bf16x8*)(sp + (long)(unsigned)(e1 & 0xffffffffu) * FDIM);
    const float v0 = __uint_as_float((unsigned)(e0 >> 32));
    const float v1 = __uint_as_float((unsigned)(e1 >> 32));
    #pragma unroll
    for (int i = 0; i < 8; ++i) acc[i] += v0 * (float)s0[i];
    #pragma unroll
    for (int i = 0; i < 8; ++i) acc[i] += v1 * (float)s1[i];
  }
  if (j < end) {
    const u64 e0 = edges[j];
    const bf16x8 s0 = *(const bf16x8*)(sp + (long)(unsigned)(e0 & 0xffffffffu) * FDIM);
    const float v0 = __uint_as_float((unsigned)(e0 >> 32));
    #pragma unroll
    for (int i = 0; i < 8; ++i) acc[i] += v0 * (float)s0[i];
  }

  *(float4*)(out + (long)r * FDIM + lane * 8) =
      make_float4(acc[0], acc[1], acc[2], acc[3]);
  *(float4*)(out + (long)r * FDIM + lane * 8 + 4) =
      make_float4(acc[4], acc[5], acc[6], acc[7]);
}

extern "C" void kernel_launch(void* const* d_in, const int* in_sizes, int n_in,
                              void* d_out, int out_size, void* d_ws, size_t ws_size,
                              hipStream_t stream) {
  const float* x    = (const float*)d_in[0];
  const float* w    = (const float*)d_in[1];
  const int*   rows = (const int*)d_in[2];
  const int*   cols = (const int*)d_in[3];
  const float* vals = (const float*)d_in[4];
  float* out = (float*)d_out;

  char* ws = (char*)d_ws;
  size_t off = 0;
  auto alloc = [&](size_t bytes) {
    void* p = ws + off;
    off += (bytes + 255) & ~(size_t)255;
    return p;
  };
  __bf16* support = (__bf16*)alloc((size_t)MPAD * FDIM * 2);      // 102.5 MB
  __bf16* wT      = (__bf16*)alloc((size_t)FDIM * FDIM * 2);      // 0.5 MB
  int*    cnt     = (int*)alloc((size_t)(NCNT + 1) * 4);          // 0.4 MB
  int*    row_off = (int*)alloc((size_t)(MPAD + 1) * 4);          // 0.4 MB
  int*    bsum    = (int*)alloc(1024 * 4);
  u64*    edges   = (u64*)alloc((size_t)N_EDGESC * 8);            // 25.6 MB
  u64*    bedges  = (u64*)alloc((size_t)N_EDGESC * 8);            // 25.6 MB
  (void)ws_size;

  k_convert_wT<<<(FDIM * FDIM + 255) / 256, 256, 0, stream>>>(w, wT);
  k_bcount<<<NBLK, 256, 0, stream>>>(rows, cnt);
  k_scan1<<<NB_SCAN, 1024, 0, stream>>>(cnt, bsum);
  k_scan2<<<1, 1024, 0, stream>>>(bsum, NB_SCAN, cnt);
  k_scan3<<<(NCNT + 255) / 256, 256, 0, stream>>>(cnt, bsum);
  k_bscatter<<<NBLK, 256, 0, stream>>>(rows, cols, vals, cnt, bedges);
  k_csr<<<NBUCKB, 256, 0, stream>>>(cnt, bedges, edges, row_off);
  k_gemm<<<(MPAD / 256) * 2, 512, 0, stream>>>(x, wT, support);
  k_spmm<<<N_NODESC / 4, 256, 0, stream>>>(row_off, edges, support, out);
}

// Round 9
// 720.258 us; speedup vs baseline: 1.7038x; 1.0355x over previous
//
#include <hip/hip_runtime.h>
#include <hip/hip_bf16.h>

#define N_NODESC 100000
#define N_EDGESC 3200000
#define FDIM 512
#define MPAD 100096   // 391 * 256 = 782 * 128
#define NBLK 256      // chunks for bucket sort
#define EPB 12500     // edges per chunk (256*12500 = 3.2M exactly)
#define NBUCKB 391    // row buckets of 256 rows
#define NCNT (NBLK * NBUCKB)   // 100096
#define NB_SCAN ((NCNT + 8191) / 8192)   // 13

typedef __attribute__((ext_vector_type(4))) float f32x4;
typedef __attribute__((ext_vector_type(8))) __bf16 bf16x8;
typedef unsigned long long u64;

__device__ __forceinline__ void gload_lds16(const void* g, void* l) {
  __builtin_amdgcn_global_load_lds(
      (const __attribute__((address_space(1))) unsigned int*)g,
      (__attribute__((address_space(3))) unsigned int*)l, 16, 0, 0);
}

// ---- fused: bucket-count chunks (blocks 0..255) + wT convert (blocks 256..511) ----
__global__ __launch_bounds__(256) void k_bcount_wt(const int* __restrict__ rows,
                                                   int* __restrict__ cnt,
                                                   const float* __restrict__ w,
                                                   __bf16* __restrict__ wT) {
  __shared__ int h[NBUCKB];
  if (blockIdx.x >= NBLK) {
    const int b = blockIdx.x - NBLK;              // 0..255
    const int i0 = b * 1024 + threadIdx.x * 4;    // 4 elems/thread
    #pragma unroll
    for (int q = 0; q < 4; ++q) {
      const int j = i0 + q;
      const int k = j >> 9, n = j & (FDIM - 1);
      wT[n * FDIM + k] = (__bf16)w[j];
    }
    return;
  }
  const int blk = blockIdx.x;
  for (int i = threadIdx.x; i < NBUCKB; i += 256) h[i] = 0;
  __syncthreads();
  const int e0 = blk * EPB;
  for (int e = e0 + threadIdx.x; e < e0 + EPB; e += 256)
    atomicAdd(&h[rows[e] >> 8], 1);
  __syncthreads();
  for (int i = threadIdx.x; i < NBUCKB; i += 256) cnt[i * NBLK + blk] = h[i];
}

// ---- multi-block exclusive scan over cnt[0..NCNT) ----
__global__ __launch_bounds__(1024) void k_scan1(int* __restrict__ d, int* __restrict__ bsum) {
  __shared__ int s[1024];
  const int t = threadIdx.x;
  const int base = blockIdx.x * 8192 + t * 8;
  int v[8];
  int sum = 0;
  #pragma unroll
  for (int k = 0; k < 8; ++k) {
    v[k] = (base + k < NCNT) ? d[base + k] : 0;
    sum += v[k];
  }
  s[t] = sum;
  __syncthreads();
  for (int dl = 1; dl < 1024; dl <<= 1) {
    int a = s[t];
    int b = (t >= dl) ? s[t - dl] : 0;
    __syncthreads();
    s[t] = a + b;
    __syncthreads();
  }
  int excl = (t == 0) ? 0 : s[t - 1];
  #pragma unroll
  for (int k = 0; k < 8; ++k) {
    if (base + k < NCNT) d[base + k] = excl;
    excl += v[k];
  }
  if (t == 1023) bsum[blockIdx.x] = s[1023];
}

__global__ __launch_bounds__(1024) void k_scan2(int* __restrict__ bsum, int nb,
                                                int* __restrict__ d) {
  __shared__ int s[1024];
  const int t = threadIdx.x;
  s[t] = (t < nb) ? bsum[t] : 0;
  __syncthreads();
  for (int dl = 1; dl < 1024; dl <<= 1) {
    int a = s[t];
    int b = (t >= dl) ? s[t - dl] : 0;
    __syncthreads();
    s[t] = a + b;
    __syncthreads();
  }
  if (t < nb) bsum[t] = (t == 0) ? 0 : s[t - 1];
  if (t == 0) d[NCNT] = s[1023];
}

__global__ void k_scan3(int* __restrict__ d, const int* __restrict__ bsum) {
  int i = blockIdx.x * 256 + threadIdx.x;
  if (i >= NCNT) return;
  d[i] += bsum[i >> 13];
}

// ---- bucket sort pass 2: scatter into (bucket,chunk) runs ----
// pack: val(32) | lrow(8) @bit17 | col(17)
__global__ __launch_bounds__(256) void k_bscatter(const int* __restrict__ rows,
                                                  const int* __restrict__ cols,
                                                  const float* __restrict__ vals,
                                                  const int* __restrict__ off,
                                                  u64* __restrict__ bedges) {
  __shared__ int lofs[NBUCKB];
  __shared__ int lcur[NBUCKB];
  const int blk = blockIdx.x;
  for (int i = threadIdx.x; i < NBUCKB; i += 256) {
    lofs[i] = off[i * NBLK + blk];
    lcur[i] = 0;
  }
  __syncthreads();
  const int e0 = blk * EPB;
  for (int e = e0 + threadIdx.x; e < e0 + EPB; e += 256) {
    const int r = rows[e];
    const int b = r >> 8;
    const int p = lofs[b] + atomicAdd(&lcur[b], 1);
    bedges[p] = ((u64)__float_as_uint(vals[e]) << 32) |
                ((u64)(r & 255) << 17) | (unsigned)cols[e];
  }
}

// ---- CSR finalize: one block per bucket; LDS hist+scan; private-region scatter ----
__global__ __launch_bounds__(256) void k_csr(const int* __restrict__ off,
                                             const u64* __restrict__ bedges,
                                             u64* __restrict__ edges,
                                             int* __restrict__ row_off) {
  __shared__ int hcnt[256];
  __shared__ int hcur[256];
  const int b = blockIdx.x;
  const int t = threadIdx.x;
  const int base  = off[b * NBLK];
  const int nextb = (b + 1 < NBUCKB) ? off[(b + 1) * NBLK] : off[NCNT];
  hcnt[t] = 0;
  __syncthreads();
  for (int j = base + t; j < nextb; j += 256)
    atomicAdd(&hcnt[(int)(bedges[j] >> 17) & 255], 1);
  __syncthreads();
  for (int d = 1; d < 256; d <<= 1) {
    int a = hcnt[t];
    int u = (t >= d) ? hcnt[t - d] : 0;
    __syncthreads();
    hcnt[t] = a + u;
    __syncthreads();
  }
  const int excl = (t == 0) ? 0 : hcnt[t - 1];
  row_off[b * 256 + t] = base + excl;
  hcur[t] = base + excl;
  __syncthreads();
  for (int j = base + t; j < nextb; j += 256) {
    const u64 e = bedges[j];
    const int lr = (int)(e >> 17) & 255;
    const int p = atomicAdd(&hcur[lr], 1);
    edges[p] = (e & 0xFFFFFFFF00000000ull) | (e & 0x1FFFFull);
  }
}

// ---- GEMM: support[MPAD][512] (bf16) = x (f32, fused convert) @ w ----
// BM=128, BN=512 (full width: x read ONCE), BK=32, 8 waves (2m x 4n)
__global__ __launch_bounds__(512) void k_gemm(const float* __restrict__ x,
                                              const __bf16* __restrict__ wT,
                                              __bf16* __restrict__ support) {
  __shared__ __bf16 lA[2][128 * 32];   // 8KB each
  __shared__ __bf16 lB[2][512 * 32];   // 32KB each, n-major: lB[n][k]
  const int tm = blockIdx.x;
  const int tid = threadIdx.x;
  const int wid = tid >> 6;
  const int lane = tid & 63;
  const int wm = wid >> 2;      // 0..1
  const int wn = wid & 3;       // 0..3

  const long rowA0 = (long)tm * 128;

  // B staging geometry (1KB chunks = 16 n-rows x 32 k)
  const int srow  = lane >> 2;
  const int skoff = (lane & 3) * 8;

  // A staging geometry: thread covers row tid>>2, k-quarter (tid&3)*8 (8 f32)
  const int arow = tid >> 2;        // 0..127
  const int ah   = (tid & 3) * 8;   // 0,8,16,24

  f32x4 acc[4][8];
  #pragma unroll
  for (int m = 0; m < 4; ++m)
    #pragma unroll
    for (int n = 0; n < 8; ++n)
      acc[m][n] = (f32x4){0.f, 0.f, 0.f, 0.f};

  const long grow = rowA0 + arow;
  const long arowc = (grow < N_NODESC) ? grow : (N_NODESC - 1);
  const bool apad = grow >= N_NODESC;

  float4 ar[2];
  auto issueA = [&](int kt) {
    const int k0 = kt * 32;
    ar[0] = *(const float4*)(x + arowc * FDIM + k0 + ah);
    ar[1] = *(const float4*)(x + arowc * FDIM + k0 + ah + 4);
  };
  auto writeA = [&](int buf) {
    bf16x8 o;
    o[0] = (__bf16)(apad ? 0.f : ar[0].x);
    o[1] = (__bf16)(apad ? 0.f : ar[0].y);
    o[2] = (__bf16)(apad ? 0.f : ar[0].z);
    o[3] = (__bf16)(apad ? 0.f : ar[0].w);
    o[4] = (__bf16)(apad ? 0.f : ar[1].x);
    o[5] = (__bf16)(apad ? 0.f : ar[1].y);
    o[6] = (__bf16)(apad ? 0.f : ar[1].z);
    o[7] = (__bf16)(apad ? 0.f : ar[1].w);
    *(bf16x8*)&lA[buf][arow * 32 + ah] = o;
  };
  auto stageB = [&](int buf, int kt) {
    const int k0 = kt * 32;
    #pragma unroll
    for (int it = 0; it < 4; ++it) {
      const int c = wid * 4 + it;   // chunk 0..31 (wave-uniform)
      const __bf16* gB = wT + (long)(c * 16 + srow) * FDIM + k0 + skoff;
      gload_lds16(gB, &lB[buf][c * 512]);
    }
  };

  issueA(0);
  stageB(0, 0);
  writeA(0);
  __syncthreads();

  const int frow = lane & 15;
  const int fk   = (lane >> 4) * 8;

  for (int kt = 0; kt < 16; ++kt) {
    const int buf = kt & 1;
    if (kt < 15) {
      issueA(kt + 1);
      stageB(buf ^ 1, kt + 1);
    }
    bf16x8 a[4], b[8];
    #pragma unroll
    for (int m = 0; m < 4; ++m)
      a[m] = *(const bf16x8*)&lA[buf][(wm * 64 + m * 16 + frow) * 32 + fk];
    #pragma unroll
    for (int n = 0; n < 8; ++n)
      b[n] = *(const bf16x8*)&lB[buf][(wn * 128 + n * 16 + frow) * 32 + fk];
    #pragma unroll
    for (int m = 0; m < 4; ++m)
      #pragma unroll
      for (int n = 0; n < 8; ++n)
        acc[m][n] = __builtin_amdgcn_mfma_f32_16x16x32_bf16(a[m], b[n], acc[m][n], 0, 0, 0);
    if (kt < 15) writeA(buf ^ 1);
    __syncthreads();
  }

  // C/D layout (m89-verified): col = lane&15, row = (lane>>4)*4 + i
  const long crow0 = (long)tm * 128 + wm * 64 + (lane >> 4) * 4;
  const int  ccol0 = wn * 128 + frow;
  #pragma unroll
  for (int m = 0; m < 4; ++m)
    #pragma unroll
    for (int n = 0; n < 8; ++n)
      #pragma unroll
      for (int i = 0; i < 4; ++i)
        support[(crow0 + m * 16 + i) * (long)FDIM + ccol0 + n * 16] = (__bf16)acc[m][n][i];
}

// ---- SpMM (R3-proven): one wave per row, lane owns 8 features, f32 acc ----
__global__ __launch_bounds__(256) void k_spmm(const int* __restrict__ row_off,
                                              const u64* __restrict__ edges,
                                              const __bf16* __restrict__ support,
                                              float* __restrict__ out) {
  const int r = blockIdx.x * 4 + (threadIdx.x >> 6);
  const int lane = threadIdx.x & 63;
  if (r >= N_NODESC) return;
  const int beg = row_off[r];
  const int end = row_off[r + 1];
  const __bf16* sp = support + lane * 8;

  float acc[8];
  #pragma unroll
  for (int i = 0; i < 8; ++i) acc[i] = 0.f;

  int j = beg;
  for (; j + 1 < end; j += 2) {
    const u64 e0 = edges[j];
    const u64 e1 = edges[j + 1];
    const bf16x8 s0 = *(const bf16x8*)(sp + (long)(unsigned)(e0 & 0xffffffffu) * FDIM);
    const bf16x8 s1 = *(const bf16x8*)(sp + (long)(unsigned)(e1 & 0xffffffffu) * FDIM);
    const float v0 = __uint_as_float((unsigned)(e0 >> 32));
    const float v1 = __uint_as_float((unsigned)(e1 >> 32));
    #pragma unroll
    for (int i = 0; i < 8; ++i) acc[i] += v0 * (float)s0[i];
    #pragma unroll
    for (int i = 0; i < 8; ++i) acc[i] += v1 * (float)s1[i];
  }
  if (j < end) {
    const u64 e0 = edges[j];
    const bf16x8 s0 = *(const bf16x8*)(sp + (long)(unsigned)(e0 & 0xffffffffu) * FDIM);
    const float v0 = __uint_as_float((unsigned)(e0 >> 32));
    #pragma unroll
    for (int i = 0; i < 8; ++i) acc[i] += v0 * (float)s0[i];
  }

  *(float4*)(out + (long)r * FDIM + lane * 8) =
      make_float4(acc[0], acc[1], acc[2], acc[3]);
  *(float4*)(out + (long)r * FDIM + lane * 8 + 4) =
      make_float4(acc[4], acc[5], acc[6], acc[7]);
}

extern "C" void kernel_launch(void* const* d_in, const int* in_sizes, int n_in,
                              void* d_out, int out_size, void* d_ws, size_t ws_size,
                              hipStream_t stream) {
  const float* x    = (const float*)d_in[0];
  const float* w    = (const float*)d_in[1];
  const int*   rows = (const int*)d_in[2];
  const int*   cols = (const int*)d_in[3];
  const float* vals = (const float*)d_in[4];
  float* out = (float*)d_out;

  char* ws = (char*)d_ws;
  size_t off = 0;
  auto alloc = [&](size_t bytes) {
    void* p = ws + off;
    off += (bytes + 255) & ~(size_t)255;
    return p;
  };
  __bf16* support = (__bf16*)alloc((size_t)MPAD * FDIM * 2);      // 102.5 MB
  __bf16* wT      = (__bf16*)alloc((size_t)FDIM * FDIM * 2);      // 0.5 MB
  int*    cnt     = (int*)alloc((size_t)(NCNT + 1) * 4);          // 0.4 MB
  int*    row_off = (int*)alloc((size_t)(MPAD + 1) * 4);          // 0.4 MB
  int*    bsum    = (int*)alloc(1024 * 4);
  u64*    edges   = (u64*)alloc((size_t)N_EDGESC * 8);            // 25.6 MB
  u64*    bedges  = (u64*)alloc((size_t)N_EDGESC * 8);            // 25.6 MB
  (void)ws_size;

  k_bcount_wt<<<NBLK + 256, 256, 0, stream>>>(rows, cnt, w, wT);
  k_scan1<<<NB_SCAN, 1024, 0, stream>>>(cnt, bsum);
  k_scan2<<<1, 1024, 0, stream>>>(bsum, NB_SCAN, cnt);
  k_scan3<<<(NCNT + 255) / 256, 256, 0, stream>>>(cnt, bsum);
  k_bscatter<<<NBLK, 256, 0, stream>>>(rows, cols, vals, cnt, bedges);
  k_csr<<<NBUCKB, 256, 0, stream>>>(cnt, bedges, edges, row_off);
  k_gemm<<<MPAD / 128, 512, 0, stream>>>(x, wT, support);
  k_spmm<<<N_NODESC / 4, 256, 0, stream>>>(row_off, edges, support, out);
}

// Round 10
// 698.445 us; speedup vs baseline: 1.7570x; 1.0312x over previous
//
#include <hip/hip_runtime.h>
#include <hip/hip_bf16.h>

#define N_NODESC 100000
#define N_EDGESC 3200000
#define FDIM 512
#define MPAD 100096   // 391 * 256 = 782 * 128
#define NBLK 256      // chunks for bucket sort
#define EPB 12500     // edges per chunk (256*12500 = 3.2M exactly)
#define NBUCKB 391    // row buckets of 256 rows
#define NCNT (NBLK * NBUCKB)   // 100096
#define NB_SCAN ((NCNT + 8191) / 8192)   // 13

typedef __attribute__((ext_vector_type(4))) float f32x4;
typedef __attribute__((ext_vector_type(8))) __bf16 bf16x8;
typedef unsigned long long u64;

__device__ __forceinline__ void gload_lds16(const void* g, void* l) {
  __builtin_amdgcn_global_load_lds(
      (const __attribute__((address_space(1))) unsigned int*)g,
      (__attribute__((address_space(3))) unsigned int*)l, 16, 0, 0);
}

// ---- fused: bucket-count chunks (blocks 0..255) + wT convert (blocks 256..511) ----
__global__ __launch_bounds__(256) void k_bcount_wt(const int* __restrict__ rows,
                                                   int* __restrict__ cnt,
                                                   const float* __restrict__ w,
                                                   __bf16* __restrict__ wT) {
  __shared__ int h[NBUCKB];
  if (blockIdx.x >= NBLK) {
    const int b = blockIdx.x - NBLK;              // 0..255
    const int i0 = b * 1024 + threadIdx.x * 4;    // 4 elems/thread
    #pragma unroll
    for (int q = 0; q < 4; ++q) {
      const int j = i0 + q;
      const int k = j >> 9, n = j & (FDIM - 1);
      wT[n * FDIM + k] = (__bf16)w[j];
    }
    return;
  }
  const int blk = blockIdx.x;
  for (int i = threadIdx.x; i < NBUCKB; i += 256) h[i] = 0;
  __syncthreads();
  const int e0 = blk * EPB;
  for (int e = e0 + threadIdx.x; e < e0 + EPB; e += 256)
    atomicAdd(&h[rows[e] >> 8], 1);
  __syncthreads();
  for (int i = threadIdx.x; i < NBUCKB; i += 256) cnt[i * NBLK + blk] = h[i];
}

// ---- multi-block exclusive scan over cnt[0..NCNT): block-local pass ----
__global__ __launch_bounds__(1024) void k_scan1(int* __restrict__ d, int* __restrict__ bsum) {
  __shared__ int s[1024];
  const int t = threadIdx.x;
  const int base = blockIdx.x * 8192 + t * 8;
  int v[8];
  int sum = 0;
  #pragma unroll
  for (int k = 0; k < 8; ++k) {
    v[k] = (base + k < NCNT) ? d[base + k] : 0;
    sum += v[k];
  }
  s[t] = sum;
  __syncthreads();
  for (int dl = 1; dl < 1024; dl <<= 1) {
    int a = s[t];
    int b = (t >= dl) ? s[t - dl] : 0;
    __syncthreads();
    s[t] = a + b;
    __syncthreads();
  }
  int excl = (t == 0) ? 0 : s[t - 1];
  #pragma unroll
  for (int k = 0; k < 8; ++k) {
    if (base + k < NCNT) d[base + k] = excl;
    excl += v[k];
  }
  if (t == 1023) bsum[blockIdx.x] = s[1023];
}

// ---- scan block sums (13 entries) -> exclusive ----
__global__ __launch_bounds__(64) void k_scan2(int* __restrict__ bsum) {
  const int t = threadIdx.x;
  int v = (t < NB_SCAN) ? bsum[t] : 0;
  #pragma unroll
  for (int dl = 1; dl < 64; dl <<= 1) {
    const int u = __shfl_up(v, dl, 64);
    if (t >= dl) v += u;
  }
  if (t < NB_SCAN) {
    const int excl = v - bsum[t];
    bsum[t] = excl;
  }
}

// ---- bucket sort pass 2: scatter into (bucket,chunk) runs; bsum folded ----
// pack: val(32) | lrow(8) @bit17 | col(17)
__global__ __launch_bounds__(512) void k_bscatter(const int* __restrict__ rows,
                                                  const int* __restrict__ cols,
                                                  const float* __restrict__ vals,
                                                  const int* __restrict__ off,
                                                  const int* __restrict__ bsum,
                                                  u64* __restrict__ bedges) {
  __shared__ int lofs[NBUCKB];
  __shared__ int lcur[NBUCKB];
  const int blk = blockIdx.x;
  for (int i = threadIdx.x; i < NBUCKB; i += 512) {
    const int idx = i * NBLK + blk;
    lofs[i] = off[idx] + bsum[idx >> 13];
    lcur[i] = 0;
  }
  __syncthreads();
  const int e0 = blk * EPB;
  for (int e = e0 + threadIdx.x; e < e0 + EPB; e += 512) {
    const int r = rows[e];
    const int b = r >> 8;
    const int p = lofs[b] + atomicAdd(&lcur[b], 1);
    bedges[p] = ((u64)__float_as_uint(vals[e]) << 32) |
                ((u64)(r & 255) << 17) | (unsigned)cols[e];
  }
}

// ---- CSR finalize: one block per bucket; LDS hist+scan; private-region scatter ----
__global__ __launch_bounds__(512) void k_csr(const int* __restrict__ off,
                                             const int* __restrict__ bsum,
                                             const u64* __restrict__ bedges,
                                             u64* __restrict__ edges,
                                             int* __restrict__ row_off) {
  __shared__ int hcnt[256];
  __shared__ int hcur[256];
  const int b = blockIdx.x;
  const int t = threadIdx.x;
  const int i0 = b * NBLK;
  const int i1 = (b + 1) * NBLK;
  const int base  = off[i0] + bsum[i0 >> 13];
  const int nextb = (b + 1 < NBUCKB) ? (off[i1] + bsum[i1 >> 13]) : N_EDGESC;
  if (t < 256) hcnt[t] = 0;
  __syncthreads();
  for (int j = base + t; j < nextb; j += 512)
    atomicAdd(&hcnt[(int)(bedges[j] >> 17) & 255], 1);
  __syncthreads();
  for (int d = 1; d < 256; d <<= 1) {
    int a = 0;
    if (t < 256) a = hcnt[t];
    int u = (t >= d && t < 256) ? hcnt[t - d] : 0;
    __syncthreads();
    if (t < 256) hcnt[t] = a + u;
    __syncthreads();
  }
  if (t < 256) {
    const int excl = (t == 0) ? 0 : hcnt[t - 1];
    row_off[b * 256 + t] = base + excl;
    hcur[t] = base + excl;
  }
  __syncthreads();
  for (int j = base + t; j < nextb; j += 512) {
    const u64 e = bedges[j];
    const int lr = (int)(e >> 17) & 255;
    const int p = atomicAdd(&hcur[lr], 1);
    edges[p] = (e & 0xFFFFFFFF0001FFFFull) & ~0x1FFE0000ull;
  }
}

// ---- GEMM: support[MPAD][512] (bf16) = x (f32, fused convert) @ w ----
// BM=128, BN=512 (full width: x read ONCE), BK=32, 8 waves (2m x 4n)
__global__ __launch_bounds__(512) void k_gemm(const float* __restrict__ x,
                                              const __bf16* __restrict__ wT,
                                              __bf16* __restrict__ support) {
  __shared__ __bf16 lA[2][128 * 32];   // 8KB each
  __shared__ __bf16 lB[2][512 * 32];   // 32KB each, n-major: lB[n][k]
  const int tm = blockIdx.x;
  const int tid = threadIdx.x;
  const int wid = tid >> 6;
  const int lane = tid & 63;
  const int wm = wid >> 2;      // 0..1
  const int wn = wid & 3;       // 0..3

  const long rowA0 = (long)tm * 128;

  // B staging geometry (1KB chunks = 16 n-rows x 32 k)
  const int srow  = lane >> 2;
  const int skoff = (lane & 3) * 8;

  // A staging geometry: thread covers row tid>>2, k-quarter (tid&3)*8 (8 f32)
  const int arow = tid >> 2;        // 0..127
  const int ah   = (tid & 3) * 8;   // 0,8,16,24

  f32x4 acc[4][8];
  #pragma unroll
  for (int m = 0; m < 4; ++m)
    #pragma unroll
    for (int n = 0; n < 8; ++n)
      acc[m][n] = (f32x4){0.f, 0.f, 0.f, 0.f};

  const long grow = rowA0 + arow;
  const long arowc = (grow < N_NODESC) ? grow : (N_NODESC - 1);
  const bool apad = grow >= N_NODESC;

  float4 ar[2];
  auto issueA = [&](int kt) {
    const int k0 = kt * 32;
    ar[0] = *(const float4*)(x + arowc * FDIM + k0 + ah);
    ar[1] = *(const float4*)(x + arowc * FDIM + k0 + ah + 4);
  };
  auto writeA = [&](int buf) {
    bf16x8 o;
    o[0] = (__bf16)(apad ? 0.f : ar[0].x);
    o[1] = (__bf16)(apad ? 0.f : ar[0].y);
    o[2] = (__bf16)(apad ? 0.f : ar[0].z);
    o[3] = (__bf16)(apad ? 0.f : ar[0].w);
    o[4] = (__bf16)(apad ? 0.f : ar[1].x);
    o[5] = (__bf16)(apad ? 0.f : ar[1].y);
    o[6] = (__bf16)(apad ? 0.f : ar[1].z);
    o[7] = (__bf16)(apad ? 0.f : ar[1].w);
    *(bf16x8*)&lA[buf][arow * 32 + ah] = o;
  };
  auto stageB = [&](int buf, int kt) {
    const int k0 = kt * 32;
    #pragma unroll
    for (int it = 0; it < 4; ++it) {
      const int c = wid * 4 + it;   // chunk 0..31 (wave-uniform)
      const __bf16* gB = wT + (long)(c * 16 + srow) * FDIM + k0 + skoff;
      gload_lds16(gB, &lB[buf][c * 512]);
    }
  };

  issueA(0);
  stageB(0, 0);
  writeA(0);
  __syncthreads();

  const int frow = lane & 15;
  const int fk   = (lane >> 4) * 8;

  for (int kt = 0; kt < 16; ++kt) {
    const int buf = kt & 1;
    if (kt < 15) {
      issueA(kt + 1);
      stageB(buf ^ 1, kt + 1);
    }
    bf16x8 a[4], b[8];
    #pragma unroll
    for (int m = 0; m < 4; ++m)
      a[m] = *(const bf16x8*)&lA[buf][(wm * 64 + m * 16 + frow) * 32 + fk];
    #pragma unroll
    for (int n = 0; n < 8; ++n)
      b[n] = *(const bf16x8*)&lB[buf][(wn * 128 + n * 16 + frow) * 32 + fk];
    #pragma unroll
    for (int m = 0; m < 4; ++m)
      #pragma unroll
      for (int n = 0; n < 8; ++n)
        acc[m][n] = __builtin_amdgcn_mfma_f32_16x16x32_bf16(a[m], b[n], acc[m][n], 0, 0, 0);
    if (kt < 15) writeA(buf ^ 1);
    __syncthreads();
  }

  // C/D layout (m89-verified): col = lane&15, row = (lane>>4)*4 + i
  const long crow0 = (long)tm * 128 + wm * 64 + (lane >> 4) * 4;
  const int  ccol0 = wn * 128 + frow;
  #pragma unroll
  for (int m = 0; m < 4; ++m)
    #pragma unroll
    for (int n = 0; n < 8; ++n)
      #pragma unroll
      for (int i = 0; i < 4; ++i)
        support[(crow0 + m * 16 + i) * (long)FDIM + ccol0 + n * 16] = (__bf16)acc[m][n][i];
}

// ---- SpMM (R3-proven): one wave per row, lane owns 8 features, f32 acc ----
__global__ __launch_bounds__(256) void k_spmm(const int* __restrict__ row_off,
                                              const u64* __restrict__ edges,
                                              const __bf16* __restrict__ support,
                                              float* __restrict__ out) {
  const int r = blockIdx.x * 4 + (threadIdx.x >> 6);
  const int lane = threadIdx.x & 63;
  if (r >= N_NODESC) return;
  const int beg = row_off[r];
  const int end = (r + 1 < N_NODESC) ? row_off[r + 1] : N_EDGESC;
  const __bf16* sp = support + lane * 8;

  float acc[8];
  #pragma unroll
  for (int i = 0; i < 8; ++i) acc[i] = 0.f;

  int j = beg;
  for (; j + 1 < end; j += 2) {
    const u64 e0 = edges[j];
    const u64 e1 = edges[j + 1];
    const bf16x8 s0 = *(const bf16x8*)(sp + (long)(unsigned)(e0 & 0xffffffffu) * FDIM);
    const bf16x8 s1 = *(const bf16x8*)(sp + (long)(unsigned)(e1 & 0xffffffffu) * FDIM);
    const float v0 = __uint_as_float((unsigned)(e0 >> 32));
    const float v1 = __uint_as_float((unsigned)(e1 >> 32));
    #pragma unroll
    for (int i = 0; i < 8; ++i) acc[i] += v0 * (float)s0[i];
    #pragma unroll
    for (int i = 0; i < 8; ++i) acc[i] += v1 * (float)s1[i];
  }
  if (j < end) {
    const u64 e0 = edges[j];
    const bf16x8 s0 = *(const bf16x8*)(sp + (long)(unsigned)(e0 & 0xffffffffu) * FDIM);
    const float v0 = __uint_as_float((unsigned)(e0 >> 32));
    #pragma unroll
    for (int i = 0; i < 8; ++i) acc[i] += v0 * (float)s0[i];
  }

  *(float4*)(out + (long)r * FDIM + lane * 8) =
      make_float4(acc[0], acc[1], acc[2], acc[3]);
  *(float4*)(out + (long)r * FDIM + lane * 8 + 4) =
      make_float4(acc[4], acc[5], acc[6], acc[7]);
}

extern "C" void kernel_launch(void* const* d_in, const int* in_sizes, int n_in,
                              void* d_out, int out_size, void* d_ws, size_t ws_size,
                              hipStream_t stream) {
  const float* x    = (const float*)d_in[0];
  const float* w    = (const float*)d_in[1];
  const int*   rows = (const int*)d_in[2];
  const int*   cols = (const int*)d_in[3];
  const float* vals = (const float*)d_in[4];
  float* out = (float*)d_out;

  char* ws = (char*)d_ws;
  size_t off = 0;
  auto alloc = [&](size_t bytes) {
    void* p = ws + off;
    off += (bytes + 255) & ~(size_t)255;
    return p;
  };
  __bf16* support = (__bf16*)alloc((size_t)MPAD * FDIM * 2);      // 102.5 MB
  __bf16* wT      = (__bf16*)alloc((size_t)FDIM * FDIM * 2);      // 0.5 MB
  int*    cnt     = (int*)alloc((size_t)(NCNT + 1) * 4);          // 0.4 MB
  int*    row_off = (int*)alloc((size_t)(MPAD + 1) * 4);          // 0.4 MB
  int*    bsum    = (int*)alloc(1024 * 4);
  u64*    edges   = (u64*)alloc((size_t)N_EDGESC * 8);            // 25.6 MB
  u64*    bedges  = (u64*)alloc((size_t)N_EDGESC * 8);            // 25.6 MB
  (void)ws_size;

  k_bcount_wt<<<NBLK + 256, 256, 0, stream>>>(rows, cnt, w, wT);
  k_scan1<<<NB_SCAN, 1024, 0, stream>>>(cnt, bsum);
  k_scan2<<<1, 64, 0, stream>>>(bsum);
  k_bscatter<<<NBLK, 512, 0, stream>>>(rows, cols, vals, cnt, bsum, bedges);
  k_csr<<<NBUCKB, 512, 0, stream>>>(cnt, bsum, bedges, edges, row_off);
  k_gemm<<<MPAD / 128, 512, 0, stream>>>(x, wT, support);
  k_spmm<<<N_NODESC / 4, 256, 0, stream>>>(row_off, edges, support, out);
}